// Round 2
// baseline (208.718 us; speedup 1.0000x reference)
//
#include <hip/hip_runtime.h>
#include <hip/hip_bf16.h>

// Problem constants (NoiseEfficientNet): B=32, Cin=96, Cout=144, H=W=56, 3x3 pad1
#define B_    32
#define CIN   96
#define COUT  144
#define H_    56
#define W_    56
#define HW    3136      // 56*56
#define NPIX  100352    // 32*3136
#define KTOT  864       // 9 taps * 96 ci
#define MT    128       // workgroup pixel tile (4 waves x 32 pixels)
#define BKP   104       // padded LDS row in shorts (208 B stride = 2-way max conflicts)

typedef short  short8  __attribute__((ext_vector_type(8)));
typedef float  floatx4 __attribute__((ext_vector_type(4)));

__device__ __forceinline__ unsigned short f2bf(float f) {
    union { float f; unsigned int u; } v; v.f = f;
    unsigned int u = v.u;
    return (unsigned short)((u + 0x7FFFu + ((u >> 16) & 1u)) >> 16);  // RNE
}

// ---------------------------------------------------------------------------
// Prep 1: x [B][Cin][H][W] fp32  ->  xT [B][H][W][Cin] bf16 (NHWC, k-contiguous)
// ---------------------------------------------------------------------------
__global__ __launch_bounds__(256) void transpose_x(const float* __restrict__ x,
                                                   unsigned short* __restrict__ xT) {
    __shared__ __align__(16) unsigned short tile[64][CIN + 8];
    int b   = blockIdx.x / 49;
    int hw0 = (blockIdx.x % 49) * 64;
    const float* xb = x + (size_t)b * CIN * HW;
    int t = threadIdx.x;
    for (int i = t; i < CIN * 16; i += 256) {
        int ci = i >> 4, seg = i & 15;
        float4 v = *(const float4*)(xb + (size_t)ci * HW + hw0 + seg * 4);
        int hwl = seg * 4;
        tile[hwl + 0][ci] = f2bf(v.x);
        tile[hwl + 1][ci] = f2bf(v.y);
        tile[hwl + 2][ci] = f2bf(v.z);
        tile[hwl + 3][ci] = f2bf(v.w);
    }
    __syncthreads();
    int row = t >> 2, part = t & 3;
    const uint4* s = (const uint4*)&tile[row][part * 24];
    uint4* d = (uint4*)(xT + ((size_t)b * HW + hw0 + row) * CIN + part * 24);
    d[0] = s[0]; d[1] = s[1]; d[2] = s[2];
}

// ---------------------------------------------------------------------------
// Prep 2: Wm [Cout][Cin][3][3] fp32 -> Wt [tap][Cout][Cin] bf16 (tap-major:
// per-tap B-tile is a contiguous 27648-short block for flat-copy staging)
// ---------------------------------------------------------------------------
__global__ __launch_bounds__(256) void prep_w(const float* __restrict__ Wm,
                                              unsigned short* __restrict__ Wt) {
    int i = blockIdx.x * 256 + threadIdx.x;
    if (i >= COUT * KTOT) return;
    int tap = i / (COUT * CIN);
    int rem = i - tap * (COUT * CIN);
    int co  = rem / CIN, ci = rem - co * CIN;
    Wt[i] = f2bf(Wm[((size_t)co * CIN + ci) * 9 + tap]);
}

// ---------------------------------------------------------------------------
// Prep 3: E [B][Cout][3][3] fp32 = bm + bx + sum_f extra[b,co,f]*boundary-class sums
// ---------------------------------------------------------------------------
__global__ __launch_bounds__(256) void prep_e(const float* __restrict__ extra,
                                              const float* __restrict__ Wx,
                                              const float* __restrict__ bm,
                                              const float* __restrict__ bx,
                                              float* __restrict__ E) {
    int i = blockIdx.x * 256 + threadIdx.x;
    if (i >= B_ * COUT) return;
    int b = i / COUT, co = i - b * COUT;
    float base = bm[co] + bx[co];
    float m[3][3] = {{0,0,0},{0,0,0},{0,0,0}};
    for (int f = 0; f < 3; ++f) {
        float e = extra[(size_t)b * (COUT * 3) + co * 3 + f];
        const float* w = Wx + ((size_t)co * 3 + f) * 9;
        for (int rc = 0; rc < 3; ++rc) {
            int kh0 = (rc == 0) ? 1 : 0;
            int kh1 = (rc == 2) ? 1 : 2;
            for (int cc = 0; cc < 3; ++cc) {
                int kw0 = (cc == 0) ? 1 : 0;
                int kw1 = (cc == 2) ? 1 : 2;
                float s = 0.f;
                for (int kh = kh0; kh <= kh1; ++kh)
                    for (int kw = kw0; kw <= kw1; ++kw)
                        s += w[kh * 3 + kw];
                m[rc][cc] += e * s;
            }
        }
    }
    float* dst = E + (size_t)i * 9;
    for (int rc = 0; rc < 3; ++rc)
        for (int cc = 0; cc < 3; ++cc)
            dst[rc * 3 + cc] = base + m[rc][cc];
}

// ---------------------------------------------------------------------------
// Main implicit GEMM, tap-granular K-loop (BK=96, 9 steps).
// Block: 256 threads = 4 waves; tile 128 pixels x 144 cout.
// Wave wv: pixels [wv*32, wv*32+32) x all 144 cout -> acc[2][9] (72 VGPR).
// Staging: per tap the A-tile is xT[(pixBase+off)*96 .. +128*96) CONTIGUOUS
// (off = dh*56+dw); copied as 1536 x 16B chunks, lane-contiguous (coalesced),
// through registers into padded LDS; halo-invalid rows zero-selected per chunk
// (chunk c -> row c/12 exactly, 12 chunks/row). B-tile contiguous from
// tap-major Wt. Next tap's loads issue before this tap's MFMAs (reg prefetch).
// ---------------------------------------------------------------------------
__global__ __launch_bounds__(256, 2) void conv_gemm(const unsigned short* __restrict__ xT,
                                                    const unsigned short* __restrict__ Wt,
                                                    const float* __restrict__ E,
                                                    float* __restrict__ out) {
    __shared__ __align__(16) unsigned short As[MT * BKP];    // 26624 B
    __shared__ __align__(16) unsigned short Bs[COUT * BKP];  // 29952 B

    int tid = threadIdx.x;
    int wv = tid >> 6, lane = tid & 63;
    int pixBase = blockIdx.x * MT;

    floatx4 acc[2][9];
    #pragma unroll
    for (int m = 0; m < 2; ++m)
        #pragma unroll
        for (int n = 0; n < 9; ++n)
            acc[m][n] = (floatx4){0.f, 0.f, 0.f, 0.f};

    // --- per-thread staging descriptors (tap-invariant) ---
    // A: chunks cA_j = tid + j*256, j<6 (1536 = 128 rows * 12 chunks)
    int aOfs[6], aH[6], aW[6];           // LDS short offset, output-pixel h,w per chunk-row
    #pragma unroll
    for (int j = 0; j < 6; ++j) {
        int c = tid + j * 256;
        int r = c / 12, col = c - r * 12;
        aOfs[j] = r * BKP + col * 8;
        int p = pixBase + r;
        int hw = p % HW;
        aH[j] = hw / W_;
        aW[j] = hw - aH[j] * W_;
    }
    // B: chunks cB_j = tid + j*256, j<7 (1728 = 144 rows * 12 chunks); j=6 only tid<192
    int bOfs[7];
    #pragma unroll
    for (int j = 0; j < 7; ++j) {
        int c = tid + j * 256;
        int r = c / 12, col = c - r * 12;
        bOfs[j] = r * BKP + col * 8;
    }
    const bool bTail = (tid < 192);      // wave-uniform (waves 0-2 yes, wave 3 no)

    const long xtMax = (long)NPIX * CIN - 8;

    uint4 pa[6], pb[7];
    // --- prologue: load tap 0 ---
    {
        const int tap = 0, dh = -1, dw = -1;
        long aBase = (long)(pixBase + dh * W_ + dw) * CIN;
        #pragma unroll
        for (int j = 0; j < 6; ++j) {
            long idx = aBase + (long)(tid + j * 256) * 8;
            idx = idx < 0 ? 0 : (idx > xtMax ? xtMax : idx);
            pa[j] = *(const uint4*)(xT + idx);
        }
        const unsigned short* wsrc = Wt + (size_t)tap * (COUT * CIN);
        #pragma unroll
        for (int j = 0; j < 6; ++j)
            pb[j] = *(const uint4*)(wsrc + (tid + j * 256) * 8);
        if (bTail) pb[6] = *(const uint4*)(wsrc + (tid + 6 * 256) * 8);
    }

    for (int tap = 0; tap < 9; ++tap) {
        int dh = tap / 3 - 1, dw = tap - (tap / 3) * 3 - 1;
        if (tap) __syncthreads();        // prior compute done reading LDS

        // ---- commit staged regs to LDS (A with halo zero-fix) ----
        #pragma unroll
        for (int j = 0; j < 6; ++j) {
            bool valid = ((unsigned)(aH[j] + dh) < H_) && ((unsigned)(aW[j] + dw) < W_);
            uint4 v = pa[j];
            if (!valid) v = (uint4){0, 0, 0, 0};
            *(uint4*)&As[aOfs[j]] = v;
        }
        #pragma unroll
        for (int j = 0; j < 6; ++j)
            *(uint4*)&Bs[bOfs[j]] = pb[j];
        if (bTail) *(uint4*)&Bs[bOfs[6]] = pb[6];
        __syncthreads();

        // ---- prefetch next tap into regs (overlaps with MFMA below) ----
        if (tap < 8) {
            int tap2 = tap + 1;
            int dh2 = tap2 / 3 - 1, dw2 = tap2 - (tap2 / 3) * 3 - 1;
            long aBase = (long)(pixBase + dh2 * W_ + dw2) * CIN;
            #pragma unroll
            for (int j = 0; j < 6; ++j) {
                long idx = aBase + (long)(tid + j * 256) * 8;
                idx = idx < 0 ? 0 : (idx > xtMax ? xtMax : idx);
                pa[j] = *(const uint4*)(xT + idx);
            }
            const unsigned short* wsrc = Wt + (size_t)tap2 * (COUT * CIN);
            #pragma unroll
            for (int j = 0; j < 6; ++j)
                pb[j] = *(const uint4*)(wsrc + (tid + j * 256) * 8);
            if (bTail) pb[6] = *(const uint4*)(wsrc + (tid + 6 * 256) * 8);
        }

        // ---- compute: 3 k-subtiles of 32, 2 m x 9 n MFMAs each ----
        int r16 = lane & 15, q8 = (lane >> 4) * 8;
        const unsigned short* Ab = &As[(wv * 32 + r16) * BKP + q8];
        const unsigned short* Bb = &Bs[r16 * BKP + q8];
        #pragma unroll
        for (int ks = 0; ks < 3; ++ks) {
            int ko = ks * 32;
            short8 a0 = *(const short8*)(Ab + ko);
            short8 a1 = *(const short8*)(Ab + 16 * BKP + ko);
            short8 bf[9];
            #pragma unroll
            for (int n = 0; n < 9; ++n)
                bf[n] = *(const short8*)(Bb + n * 16 * BKP + ko);
            #pragma unroll
            for (int n = 0; n < 9; ++n) {
                acc[0][n] = __builtin_amdgcn_mfma_f32_16x16x32_bf16(a0, bf[n], acc[0][n], 0, 0, 0);
                acc[1][n] = __builtin_amdgcn_mfma_f32_16x16x32_bf16(a1, bf[n], acc[1][n], 0, 0, 0);
            }
        }
    }

    // ---- epilogue: out = acc + E[b][co][rc(h)][cc(w)] ----
    int q = lane >> 4;
    int col = lane & 15;
    #pragma unroll
    for (int m = 0; m < 2; ++m) {
        int p0 = pixBase + wv * 32 + m * 16 + q * 4;   // 4-aligned; 56%4==0, 3136%4==0
        int b  = p0 / HW;
        int hw0 = p0 - b * HW;
        int h = hw0 / W_;
        int w0 = hw0 - h * W_;
        int rc = (h == 0) ? 0 : ((h == H_ - 1) ? 2 : 1);
        int cc0 = (w0 == 0) ? 0 : ((w0 == W_ - 1) ? 2 : 1);
        int cc1 = (w0 + 1 == W_ - 1) ? 2 : 1;
        int cc2 = (w0 + 2 == W_ - 1) ? 2 : 1;
        int cc3 = (w0 + 3 == W_ - 1) ? 2 : 1;
        #pragma unroll
        for (int n = 0; n < 9; ++n) {
            int co = n * 16 + col;
            const float* Eb = E + ((size_t)b * COUT + co) * 9 + rc * 3;
            float4 v;
            v.x = acc[m][n][0] + Eb[cc0];
            v.y = acc[m][n][1] + Eb[cc1];
            v.z = acc[m][n][2] + Eb[cc2];
            v.w = acc[m][n][3] + Eb[cc3];
            *(float4*)(out + ((size_t)b * COUT + co) * HW + hw0) = v;
        }
    }
}

// ---------------------------------------------------------------------------
extern "C" void kernel_launch(void* const* d_in, const int* in_sizes, int n_in,
                              void* d_out, int out_size, void* d_ws, size_t ws_size,
                              hipStream_t stream) {
    const float* x     = (const float*)d_in[0];
    const float* extra = (const float*)d_in[1];
    const float* Wm    = (const float*)d_in[2];
    const float* bm    = (const float*)d_in[3];
    const float* Wx    = (const float*)d_in[4];
    const float* bx    = (const float*)d_in[5];
    float* out = (float*)d_out;

    const size_t XT_BYTES = (size_t)NPIX * CIN * 2;   // 19,267,584
    const size_t WT_BYTES = (size_t)COUT * KTOT * 2;  //    248,832
    const size_t E_BYTES  = (size_t)B_ * COUT * 9 * 4;//    165,888
    if (ws_size < XT_BYTES + WT_BYTES + E_BYTES) return;

    unsigned short* xT = (unsigned short*)d_ws;
    unsigned short* Wt = (unsigned short*)((char*)d_ws + XT_BYTES);
    float*          E  = (float*)((char*)d_ws + XT_BYTES + WT_BYTES);

    transpose_x<<<B_ * 49, 256, 0, stream>>>(x, xT);
    prep_w<<<(COUT * KTOT + 255) / 256, 256, 0, stream>>>(Wm, Wt);
    prep_e<<<(B_ * COUT + 255) / 256, 256, 0, stream>>>(extra, Wx, bm, bx, E);
    conv_gemm<<<NPIX / MT, 256, 0, stream>>>(xT, Wt, E, out);
}

// Round 3
// 169.903 us; speedup vs baseline: 1.2285x; 1.2285x over previous
//
#include <hip/hip_runtime.h>
#include <hip/hip_bf16.h>

// Problem constants (NoiseEfficientNet): B=32, Cin=96, Cout=144, H=W=56, 3x3 pad1
#define B_    32
#define CIN   96
#define COUT  144
#define H_    56
#define W_    56
#define HW    3136      // 56*56
#define NPIX  100352    // 32*3136
#define KTOT  864       // 9 taps * 96 ci
#define MT    128       // workgroup pixel tile (4 waves x 32 pixels each)
#define TAPSZ (COUT*CIN) // 13824 shorts per tap in Wt

typedef short  short8  __attribute__((ext_vector_type(8)));
typedef float  floatx4 __attribute__((ext_vector_type(4)));

// 16B of guaranteed zeros for halo-granule redirection (zero-init at load)
__device__ __attribute__((aligned(64))) float g_zero[16];

__device__ __forceinline__ unsigned short f2bf(float f) {
    union { float f; unsigned int u; } v; v.f = f;
    unsigned int u = v.u;
    return (unsigned short)((u + 0x7FFFu + ((u >> 16) & 1u)) >> 16);  // RNE
}

// async global->LDS, 16B per lane; LDS dest must be lane-linear per wave
__device__ __forceinline__ void glds16(const void* g, void* l) {
    __builtin_amdgcn_global_load_lds(
        (const __attribute__((address_space(1))) unsigned int*)g,
        (__attribute__((address_space(3))) unsigned int*)l, 16, 0, 0);
}

// ---------------------------------------------------------------------------
// Fused prep kernel. Grid = 1568 (transpose) + 486 (weights) + 18 (E table).
//   transpose: x [B][96][56][56] f32 -> xT [B][56][56][96] bf16
//   weights:   Wm [144][96][3][3] f32 -> Wt [tap][co][ci] bf16 (tap-major)
//   E table:   E [B][144][3][3] f32 (boundary-class constants for extra path)
// ---------------------------------------------------------------------------
#define TB 1568
#define WB 486
__global__ __launch_bounds__(256) void prep_all(const float* __restrict__ x,
                                                unsigned short* __restrict__ xT,
                                                const float* __restrict__ Wm,
                                                unsigned short* __restrict__ Wt,
                                                const float* __restrict__ extra,
                                                const float* __restrict__ Wx,
                                                const float* __restrict__ bm,
                                                const float* __restrict__ bx,
                                                float* __restrict__ E) {
    __shared__ __align__(16) unsigned short tile[64][CIN + 8];
    int blk = blockIdx.x;
    int t = threadIdx.x;
    if (blk < TB) {
        int b   = blk / 49;
        int hw0 = (blk % 49) * 64;
        const float* xb = x + (size_t)b * CIN * HW;
        for (int i = t; i < CIN * 16; i += 256) {
            int ci = i >> 4, seg = i & 15;
            float4 v = *(const float4*)(xb + (size_t)ci * HW + hw0 + seg * 4);
            int hwl = seg * 4;
            tile[hwl + 0][ci] = f2bf(v.x);
            tile[hwl + 1][ci] = f2bf(v.y);
            tile[hwl + 2][ci] = f2bf(v.z);
            tile[hwl + 3][ci] = f2bf(v.w);
        }
        __syncthreads();
        int row = t >> 2, part = t & 3;
        const uint4* s = (const uint4*)&tile[row][part * 24];
        uint4* d = (uint4*)(xT + ((size_t)b * HW + hw0 + row) * CIN + part * 24);
        d[0] = s[0]; d[1] = s[1]; d[2] = s[2];
    } else if (blk < TB + WB) {
        int i = (blk - TB) * 256 + t;      // [0, 124416)
        int tap = i / TAPSZ;
        int rem = i - tap * TAPSZ;
        int co  = rem / CIN, ci = rem - co * CIN;
        Wt[i] = f2bf(Wm[((size_t)co * CIN + ci) * 9 + tap]);
    } else {
        int i = (blk - TB - WB) * 256 + t; // [0, 4608)
        int b = i / COUT, co = i - b * COUT;
        float base = bm[co] + bx[co];
        float m[3][3] = {{0,0,0},{0,0,0},{0,0,0}};
        for (int f = 0; f < 3; ++f) {
            float e = extra[(size_t)b * (COUT * 3) + co * 3 + f];
            const float* w = Wx + ((size_t)co * 3 + f) * 9;
            for (int rc = 0; rc < 3; ++rc) {
                int kh0 = (rc == 0) ? 1 : 0;
                int kh1 = (rc == 2) ? 1 : 2;
                for (int cc = 0; cc < 3; ++cc) {
                    int kw0 = (cc == 0) ? 1 : 0;
                    int kw1 = (cc == 2) ? 1 : 2;
                    float s = 0.f;
                    for (int kh = kh0; kh <= kh1; ++kh)
                        for (int kw = kw0; kw <= kw1; ++kw)
                            s += w[kh * 3 + kw];
                    m[rc][cc] += e * s;
                }
            }
        }
        float* dst = E + (size_t)i * 9;
        for (int rc = 0; rc < 3; ++rc)
            for (int cc = 0; cc < 3; ++cc)
                dst[rc * 3 + cc] = base + m[rc][cc];
    }
}

// ---------------------------------------------------------------------------
// Main implicit GEMM, tap-granular K-loop (BK=96, 9 steps), glds staging.
// Block: 256 thr = 4 waves; tile 128 px x 144 co; wave = 32 px x 144 co.
// LDS: As[128][96], Bs[144][96] bf16, unpadded, rotation-12 granule swizzle:
//   16B granule g of row r lives at slot (g + r) % 12  -> 2-way max conflicts
//   and lane-linear destinations compatible with global_load_lds.
// Halo rows (h+dh or w+dw out of range, incl. batch boundaries): their
// granules' global source is redirected to g_zero (16 zero bytes).
// Epilogue stages 16-co chunks through LDS so every global store instruction
// writes 512B-contiguous per co-plane (full 128B lines -> no write amp).
// ---------------------------------------------------------------------------
__global__ __launch_bounds__(256, 3) void conv_gemm(const unsigned short* __restrict__ xT,
                                                    const unsigned short* __restrict__ Wt,
                                                    const float* __restrict__ E,
                                                    float* __restrict__ out) {
    __shared__ __align__(16) unsigned char smem[52224];
    unsigned short* As = (unsigned short*)smem;            // 128*96*2 = 24576 B
    unsigned short* Bs = (unsigned short*)(smem + 24576);  // 144*96*2 = 27648 B

    int tid = threadIdx.x;
    int wv = tid >> 6, lane = tid & 63;
    int pixBase = blockIdx.x * MT;
    int r16 = lane & 15, q = lane >> 4;

    floatx4 acc[2][9];
    #pragma unroll
    for (int m = 0; m < 2; ++m)
        #pragma unroll
        for (int n = 0; n < 9; ++n)
            acc[m][n] = (floatx4){0.f, 0.f, 0.f, 0.f};

    // ---- per-thread staging descriptors (tap-invariant) ----
    // A granules: l = tid + j*256, j<6  (1536 = 128 rows * 12 granules)
    int aIdx[6], aH[6], aW[6];
    #pragma unroll
    for (int j = 0; j < 6; ++j) {
        int l = tid + j * 256;
        int r = l / 12, s = l - r * 12;
        int g = s - (r % 12); if (g < 0) g += 12;          // data granule at slot s
        int p = pixBase + r;
        aIdx[j] = p * CIN + g * 8;
        int hw = p % HW;
        aH[j] = hw / W_;
        aW[j] = hw - aH[j] * W_;
    }
    // B granules: l = tid + j*256, j<7 (1728 = 144 rows * 12); j=6 only tid<192
    int bIdx[7];
    #pragma unroll
    for (int j = 0; j < 7; ++j) {
        int l = tid + j * 256;
        int r = l / 12, s = l - r * 12;
        int g = s - (r % 12); if (g < 0) g += 12;
        bIdx[j] = r * CIN + g * 8;
    }
    const bool bTail = (tid < 192);  // waves 0-2 handle granules [1536,1728)

    // ---- precomputed MFMA read bases + rotation slots ----
    int aBase[2], s0a[2];
    #pragma unroll
    for (int m = 0; m < 2; ++m) {
        int row = wv * 32 + m * 16 + r16;
        aBase[m] = row * CIN;
        s0a[m] = (row + q) % 12;
    }
    int bBase[9], s0b[9];
    #pragma unroll
    for (int n = 0; n < 9; ++n) {
        int row = n * 16 + r16;
        bBase[n] = row * CIN;
        s0b[n] = (row + q) % 12;
    }

    for (int tap = 0; tap < 9; ++tap) {
        int dh = tap / 3 - 1, dw = tap - (tap / 3) * 3 - 1;
        int off96 = (dh * W_ + dw) * CIN;
        if (tap) __syncthreads();        // prior MFMA done reading LDS

        // ---- issue async global->LDS staging ----
        #pragma unroll
        for (int j = 0; j < 6; ++j) {
            bool valid = ((unsigned)(aH[j] + dh) < H_) && ((unsigned)(aW[j] + dw) < W_);
            const unsigned short* src = valid ? (xT + aIdx[j] + off96)
                                              : (const unsigned short*)g_zero;
            glds16(src, As + tid * 8 + j * 2048);
        }
        const unsigned short* wsrc = Wt + tap * TAPSZ;
        #pragma unroll
        for (int j = 0; j < 6; ++j)
            glds16(wsrc + bIdx[j], Bs + tid * 8 + j * 2048);
        if (bTail)
            glds16(wsrc + bIdx[6], Bs + tid * 8 + 6 * 2048);

        __builtin_amdgcn_s_waitcnt(0x0F70);  // vmcnt(0): glds landed in LDS
        __syncthreads();

        // ---- compute: 3 k-subtiles of 32, 2m x 9n MFMAs each ----
        #pragma unroll
        for (int ks = 0; ks < 3; ++ks) {
            short8 a[2], bf[9];
            #pragma unroll
            for (int m = 0; m < 2; ++m) {
                int slot = s0a[m] + 4 * ks; if (slot >= 12) slot -= 12;
                a[m] = *(const short8*)&As[aBase[m] + slot * 8];
            }
            #pragma unroll
            for (int n = 0; n < 9; ++n) {
                int slot = s0b[n] + 4 * ks; if (slot >= 12) slot -= 12;
                bf[n] = *(const short8*)&Bs[bBase[n] + slot * 8];
            }
            #pragma unroll
            for (int n = 0; n < 9; ++n) {
                acc[0][n] = __builtin_amdgcn_mfma_f32_16x16x32_bf16(a[0], bf[n], acc[0][n], 0, 0, 0);
                acc[1][n] = __builtin_amdgcn_mfma_f32_16x16x32_bf16(a[1], bf[n], acc[1][n], 0, 0, 0);
            }
        }
    }

    // ---- epilogue: stage 16-co chunks through LDS, store 512B-contiguous ----
    __syncthreads();                      // all MFMA done; smem reused as Ct
    float* Ct = (float*)smem;             // [16 co][132 px] = 8448 B

    // per-m pixel/boundary decode (n-invariant)
    int pB[2], pHW[2], pRC[2], pCC[2][4];
    #pragma unroll
    for (int m = 0; m < 2; ++m) {
        int p0 = pixBase + wv * 32 + m * 16 + q * 4;
        int b  = p0 / HW;
        int hw0 = p0 - b * HW;
        int h = hw0 / W_;
        int w0 = hw0 - h * W_;
        pB[m] = b; pHW[m] = hw0;
        pRC[m] = (h == 0) ? 0 : ((h == H_ - 1) ? 2 : 1);
        pCC[m][0] = (w0 == 0) ? 0 : ((w0 == W_ - 1) ? 2 : 1);
        pCC[m][1] = (w0 + 1 == W_ - 1) ? 2 : 1;
        pCC[m][2] = (w0 + 2 == W_ - 1) ? 2 : 1;
        pCC[m][3] = (w0 + 3 == W_ - 1) ? 2 : 1;
    }
    int coT = tid >> 4, px8 = (tid & 15) * 8;
    int pS = pixBase + px8;               // 8-px store run (never straddles batch)
    int bS = pS / HW;
    int hwS = pS - bS * HW;

    #pragma unroll
    for (int n = 0; n < 9; ++n) {
        if (n) __syncthreads();           // prev chunk's reads done
        #pragma unroll
        for (int m = 0; m < 2; ++m) {
            int co = n * 16 + r16;
            const float* Eb = E + ((size_t)pB[m] * COUT + co) * 9 + pRC[m] * 3;
            float4 v;
            v.x = acc[m][n][0] + Eb[pCC[m][0]];
            v.y = acc[m][n][1] + Eb[pCC[m][1]];
            v.z = acc[m][n][2] + Eb[pCC[m][2]];
            v.w = acc[m][n][3] + Eb[pCC[m][3]];
            *(float4*)&Ct[r16 * 132 + wv * 32 + m * 16 + q * 4] = v;
        }
        __syncthreads();
        float4 v0 = *(const float4*)&Ct[coT * 132 + px8];
        float4 v1 = *(const float4*)&Ct[coT * 132 + px8 + 4];
        float* dst = out + ((size_t)bS * COUT + n * 16 + coT) * HW + hwS;
        *(float4*)dst = v0;
        *(float4*)(dst + 4) = v1;
    }
}

// ---------------------------------------------------------------------------
extern "C" void kernel_launch(void* const* d_in, const int* in_sizes, int n_in,
                              void* d_out, int out_size, void* d_ws, size_t ws_size,
                              hipStream_t stream) {
    const float* x     = (const float*)d_in[0];
    const float* extra = (const float*)d_in[1];
    const float* Wm    = (const float*)d_in[2];
    const float* bm    = (const float*)d_in[3];
    const float* Wx    = (const float*)d_in[4];
    const float* bx    = (const float*)d_in[5];
    float* out = (float*)d_out;

    const size_t XT_BYTES = (size_t)NPIX * CIN * 2;    // 19,267,584
    const size_t WT_BYTES = (size_t)COUT * KTOT * 2;   //    248,832
    const size_t E_BYTES  = (size_t)B_ * COUT * 9 * 4; //    165,888
    if (ws_size < XT_BYTES + WT_BYTES + E_BYTES) return;

    unsigned short* xT = (unsigned short*)d_ws;
    unsigned short* Wt = (unsigned short*)((char*)d_ws + XT_BYTES);
    float*          E  = (float*)((char*)d_ws + XT_BYTES + WT_BYTES);

    prep_all<<<TB + WB + 18, 256, 0, stream>>>(x, xT, Wm, Wt, extra, Wx, bm, bx, E);
    conv_gemm<<<NPIX / MT, 256, 0, stream>>>(xT, Wt, E, out);
}

// Round 4
// 159.754 us; speedup vs baseline: 1.3065x; 1.0635x over previous
//
#include <hip/hip_runtime.h>
#include <hip/hip_bf16.h>

// Problem constants (NoiseEfficientNet): B=32, Cin=96, Cout=144, H=W=56, 3x3 pad1
#define B_    32
#define CIN   96
#define COUT  144
#define H_    56
#define W_    56
#define HW    3136      // 56*56
#define NPIX  100352    // 32*3136
#define KTOT  864       // 9 taps * 96 ci
#define MT    256       // workgroup pixel tile (4 waves x 64 pixels each)
#define TAPSZ (COUT*CIN) // 13824 shorts per tap in Wt

typedef short  short8  __attribute__((ext_vector_type(8)));
typedef float  floatx4 __attribute__((ext_vector_type(4)));

// zero pool for halo-fragment redirection (zero-initialized device memory).
// Max offset added to the redirected base: ks*32 + q*8 + 8 = 96 shorts = 192 B.
__device__ __attribute__((aligned(64))) float g_zero[64];   // 256 B of zeros

__device__ __forceinline__ unsigned short f2bf(float f) {
    union { float f; unsigned int u; } v; v.f = f;
    unsigned int u = v.u;
    return (unsigned short)((u + 0x7FFFu + ((u >> 16) & 1u)) >> 16);  // RNE
}

// async global->LDS, 16B per lane; LDS dest is wave-uniform base + lane*16
__device__ __forceinline__ void glds16(const void* g, void* l) {
    __builtin_amdgcn_global_load_lds(
        (const __attribute__((address_space(1))) unsigned int*)g,
        (__attribute__((address_space(3))) unsigned int*)l, 16, 0, 0);
}

// ---------------------------------------------------------------------------
// Fused prep kernel (unchanged from round 3 — verified correct).
//   transpose: x [B][96][56][56] f32 -> xT [B][56][56][96] bf16
//   weights:   Wm [144][96][3][3] f32 -> Wt [tap][co][ci] bf16 (tap-major)
//   E table:   E [B][144][3][3] f32 (boundary-class constants for extra path)
// ---------------------------------------------------------------------------
#define TB 1568
#define WB 486
__global__ __launch_bounds__(256) void prep_all(const float* __restrict__ x,
                                                unsigned short* __restrict__ xT,
                                                const float* __restrict__ Wm,
                                                unsigned short* __restrict__ Wt,
                                                const float* __restrict__ extra,
                                                const float* __restrict__ Wx,
                                                const float* __restrict__ bm,
                                                const float* __restrict__ bx,
                                                float* __restrict__ E) {
    __shared__ __align__(16) unsigned short tile[64][CIN + 8];
    int blk = blockIdx.x;
    int t = threadIdx.x;
    if (blk < TB) {
        int b   = blk / 49;
        int hw0 = (blk % 49) * 64;
        const float* xb = x + (size_t)b * CIN * HW;
        for (int i = t; i < CIN * 16; i += 256) {
            int ci = i >> 4, seg = i & 15;
            float4 v = *(const float4*)(xb + (size_t)ci * HW + hw0 + seg * 4);
            int hwl = seg * 4;
            tile[hwl + 0][ci] = f2bf(v.x);
            tile[hwl + 1][ci] = f2bf(v.y);
            tile[hwl + 2][ci] = f2bf(v.z);
            tile[hwl + 3][ci] = f2bf(v.w);
        }
        __syncthreads();
        int row = t >> 2, part = t & 3;
        const uint4* s = (const uint4*)&tile[row][part * 24];
        uint4* d = (uint4*)(xT + ((size_t)b * HW + hw0 + row) * CIN + part * 24);
        d[0] = s[0]; d[1] = s[1]; d[2] = s[2];
    } else if (blk < TB + WB) {
        int i = (blk - TB) * 256 + t;      // [0, 124416)
        int tap = i / TAPSZ;
        int rem = i - tap * TAPSZ;
        int co  = rem / CIN, ci = rem - co * CIN;
        Wt[i] = f2bf(Wm[((size_t)co * CIN + ci) * 9 + tap]);
    } else {
        int i = (blk - TB - WB) * 256 + t; // [0, 4608)
        int b = i / COUT, co = i - b * COUT;
        float base = bm[co] + bx[co];
        float m[3][3] = {{0,0,0},{0,0,0},{0,0,0}};
        for (int f = 0; f < 3; ++f) {
            float e = extra[(size_t)b * (COUT * 3) + co * 3 + f];
            const float* w = Wx + ((size_t)co * 3 + f) * 9;
            for (int rc = 0; rc < 3; ++rc) {
                int kh0 = (rc == 0) ? 1 : 0;
                int kh1 = (rc == 2) ? 1 : 2;
                for (int cc = 0; cc < 3; ++cc) {
                    int kw0 = (cc == 0) ? 1 : 0;
                    int kw1 = (cc == 2) ? 1 : 2;
                    float s = 0.f;
                    for (int kh = kh0; kh <= kh1; ++kh)
                        for (int kw = kw0; kw <= kw1; ++kw)
                            s += w[kh * 3 + kw];
                    m[rc][cc] += e * s;
                }
            }
        }
        float* dst = E + (size_t)i * 9;
        for (int rc = 0; rc < 3; ++rc)
            for (int cc = 0; cc < 3; ++cc)
                dst[rc * 3 + cc] = base + m[rc][cc];
    }
}

// ---------------------------------------------------------------------------
// Main implicit GEMM v2.
// Block: 256 thr = 4 waves; tile 256 px x 144 co; wave = 64 px x 144 co
// (acc[4][9], B LDS traffic amortized over m=64 -> half of round 3).
// A fragments: DIRECT global->VGPR b128 loads (no LDS), register
// double-buffered across taps; halo pixels redirect to g_zero.
// B: LDS double-buffer, [granule g=ks*4+q][co] layout (uniform bank spread),
// staged via global_load_lds; next tap's B-glds + A-loads issue right after
// the barrier, then 108 MFMAs run while they fly; the NEXT __syncthreads'
// implicit vmcnt(0) drains them after a full compute phase (true pipeline).
// Epilogue: direct stores from acc D-layout (col=lane&15 -> co,
// row=(lane>>4)*4+reg -> px), 64B runs per co per instr, L2-merged.
// ---------------------------------------------------------------------------
__global__ __launch_bounds__(256, 1) void conv_gemm(const unsigned short* __restrict__ xT,
                                                    const unsigned short* __restrict__ Wt,
                                                    const float* __restrict__ E,
                                                    float* __restrict__ out) {
    __shared__ __align__(16) unsigned short Bs[2 * TAPSZ];   // 2 x 27648 B

    int tid = threadIdx.x;
    int wv = tid >> 6, lane = tid & 63;
    int r16 = lane & 15, q = lane >> 4;
    int pixBase = blockIdx.x * MT;

    floatx4 acc[4][9];
    #pragma unroll
    for (int m = 0; m < 4; ++m)
        #pragma unroll
        for (int n = 0; n < 9; ++n)
            acc[m][n] = (floatx4){0.f, 0.f, 0.f, 0.f};

    // ---- A addressing (per ms-subtile, tap-invariant) ----
    int aIdx[4], hA[4], wA[4];
    #pragma unroll
    for (int ms = 0; ms < 4; ++ms) {
        int p = pixBase + wv * 64 + ms * 16 + r16;   // A-frag m = lane&15
        aIdx[ms] = p * CIN;
        int hw = p % HW;
        hA[ms] = hw / W_;
        wA[ms] = hw - hA[ms] * W_;
    }
    const unsigned short* gz = (const unsigned short*)g_zero;

    // ---- B staging descriptors: slot s = tid + j*256 -> (g = s/144, co = s%144)
    int bSrc[7];
    #pragma unroll
    for (int j = 0; j < 7; ++j) {
        int s = tid + j * 256;
        int g = s / COUT, co = s - g * COUT;
        bSrc[j] = co * CIN + g * 8;
    }
    const bool bTail = (tid < 192);   // waves 0-2 stage slots [1536,1728)

    // B-frag read base (shorts): addr(n,ks) = Bp + ks*4608 + n*128
    const unsigned short* BpBase = Bs + (q * COUT + r16) * 8;

    // ---- double-buffered A fragments in registers ----
    short8 a[2][4][3];

    // ---- prologue: stage tap 0 ----
    {
        const unsigned short* wsrc = Wt;
        #pragma unroll
        for (int j = 0; j < 6; ++j)
            glds16(wsrc + bSrc[j], (void*)(Bs + tid * 8 + j * 2048));
        if (bTail)
            glds16(wsrc + bSrc[6], (void*)(Bs + tid * 8 + 6 * 2048));
        const int dh = -1, dw = -1, off = (dh * W_ + dw) * CIN;
        #pragma unroll
        for (int ms = 0; ms < 4; ++ms) {
            bool valid = ((unsigned)(hA[ms] + dh) < H_) && ((unsigned)(wA[ms] + dw) < W_);
            const unsigned short* base = valid ? (xT + aIdx[ms] + off) : gz;
            #pragma unroll
            for (int ks = 0; ks < 3; ++ks)
                a[0][ms][ks] = *(const short8*)(base + ks * 32 + q * 8);
        }
    }
    __syncthreads();   // tap 0 B in LDS, A in regs

    #pragma unroll
    for (int tap = 0; tap < 9; ++tap) {
        const int cur = tap & 1, nxt = cur ^ 1;

        // ---- issue next tap's B-glds + A-loads (fly during MFMAs below) ----
        if (tap < 8) {
            const int tap2 = tap + 1;
            const int dh2 = tap2 / 3 - 1, dw2 = tap2 - (tap2 / 3) * 3 - 1;
            const unsigned short* wsrc = Wt + tap2 * TAPSZ;
            unsigned short* bd = Bs + nxt * TAPSZ;
            #pragma unroll
            for (int j = 0; j < 6; ++j)
                glds16(wsrc + bSrc[j], (void*)(bd + tid * 8 + j * 2048));
            if (bTail)
                glds16(wsrc + bSrc[6], (void*)(bd + tid * 8 + 6 * 2048));
            const int off2 = (dh2 * W_ + dw2) * CIN;
            #pragma unroll
            for (int ms = 0; ms < 4; ++ms) {
                bool valid = ((unsigned)(hA[ms] + dh2) < H_) && ((unsigned)(wA[ms] + dw2) < W_);
                const unsigned short* base = valid ? (xT + aIdx[ms] + off2) : gz;
                #pragma unroll
                for (int ks = 0; ks < 3; ++ks)
                    a[nxt][ms][ks] = *(const short8*)(base + ks * 32 + q * 8);
            }
        }

        // ---- compute tap: 3 k-subtiles x (9 n x 4 ms) MFMAs ----
        const unsigned short* Bp = BpBase + cur * TAPSZ;
        #pragma unroll
        for (int ks = 0; ks < 3; ++ks) {
            short8 bf[9];
            #pragma unroll
            for (int n = 0; n < 9; ++n)
                bf[n] = *(const short8*)(Bp + ks * 4608 + n * 128);
            #pragma unroll
            for (int n = 0; n < 9; ++n)
                #pragma unroll
                for (int ms = 0; ms < 4; ++ms)
                    acc[ms][n] = __builtin_amdgcn_mfma_f32_16x16x32_bf16(
                        a[cur][ms][ks], bf[n], acc[ms][n], 0, 0, 0);
        }

        // drain next tap's glds (had the whole compute phase to land) +
        // release cur buffer for tap+2's staging
        __syncthreads();
    }

    // ---- epilogue: direct stores, out = acc + E[b][co][rc(h)][cc(w)] ----
    #pragma unroll
    for (int ms = 0; ms < 4; ++ms) {
        int p0 = pixBase + wv * 64 + ms * 16 + q * 4;  // D-layout row = q*4+reg
        int b  = p0 / HW;
        int hw0 = p0 - b * HW;                          // 4-aligned, no b straddle
        int h = hw0 / W_;
        int w0 = hw0 - h * W_;                          // 4-aligned, no row straddle
        int rc = (h == 0) ? 0 : ((h == H_ - 1) ? 2 : 1);
        int cc0 = (w0 == 0) ? 0 : ((w0 == W_ - 1) ? 2 : 1);
        int cc1 = (w0 + 1 == W_ - 1) ? 2 : 1;
        int cc2 = (w0 + 2 == W_ - 1) ? 2 : 1;
        int cc3 = (w0 + 3 == W_ - 1) ? 2 : 1;
        const float* Ebase = E + (size_t)b * COUT * 9 + rc * 3;
        float* outB = out + (size_t)b * COUT * HW + hw0;
        #pragma unroll
        for (int n = 0; n < 9; ++n) {
            int co = n * 16 + r16;                      // D-layout col = lane&15
            const float* Eb = Ebase + co * 9;
            float4 v;
            v.x = acc[ms][n][0] + Eb[cc0];
            v.y = acc[ms][n][1] + Eb[cc1];
            v.z = acc[ms][n][2] + Eb[cc2];
            v.w = acc[ms][n][3] + Eb[cc3];
            *(float4*)(outB + (size_t)co * HW) = v;
        }
    }
}

// ---------------------------------------------------------------------------
extern "C" void kernel_launch(void* const* d_in, const int* in_sizes, int n_in,
                              void* d_out, int out_size, void* d_ws, size_t ws_size,
                              hipStream_t stream) {
    const float* x     = (const float*)d_in[0];
    const float* extra = (const float*)d_in[1];
    const float* Wm    = (const float*)d_in[2];
    const float* bm    = (const float*)d_in[3];
    const float* Wx    = (const float*)d_in[4];
    const float* bx    = (const float*)d_in[5];
    float* out = (float*)d_out;

    const size_t XT_BYTES = (size_t)NPIX * CIN * 2;    // 19,267,584
    const size_t WT_BYTES = (size_t)COUT * KTOT * 2;   //    248,832
    const size_t E_BYTES  = (size_t)B_ * COUT * 9 * 4; //    165,888
    if (ws_size < XT_BYTES + WT_BYTES + E_BYTES) return;

    unsigned short* xT = (unsigned short*)d_ws;
    unsigned short* Wt = (unsigned short*)((char*)d_ws + XT_BYTES);
    float*          E  = (float*)((char*)d_ws + XT_BYTES + WT_BYTES);

    prep_all<<<TB + WB + 18, 256, 0, stream>>>(x, xT, Wm, Wt, extra, Wx, bm, bx, E);
    conv_gemm<<<NPIX / MT, 256, 0, stream>>>(xT, Wt, E, out);
}